// Round 1
// baseline (181.810 us; speedup 1.0000x reference)
//
#include <hip/hip_runtime.h>

// Problem constants (from reference): x(32,64,128,128) fp32, W(128,64,3,3), bias(128)
// out = min_co((conv_valid(x,W) + bias) * 0.5) -> (32,1,126,126) fp32
constexpr int CN   = 32;
constexpr int CIN  = 64;
constexpr int CH   = 128;
constexpr int CW   = 128;
constexpr int COUT = 128;
constexpr int OHh  = 126;
constexpr int OWw  = 126;
constexpr int KTOT = 576;   // 64*3*3
constexpr int KSTEP = 32;
constexpr int NSTEPS = KTOT / KSTEP;  // 18

typedef __attribute__((ext_vector_type(8))) short bf16x8;
typedef __attribute__((ext_vector_type(4))) float f32x4;

__device__ __forceinline__ unsigned short f2bf(float f) {
  union { float f; unsigned u; } v; v.f = f;
  unsigned u = v.u;
  u += 0x7FFFu + ((u >> 16) & 1u);   // round-to-nearest-even
  return (unsigned short)(u >> 16);
}

// Pre-permute + convert W to bf16 in k' = kw*192 + ci*3 + kh order:
// Wt[co][k'] so the main kernel stages it with aligned 16B vector loads.
__global__ void prep_wt_kernel(const float* __restrict__ w,
                               unsigned short* __restrict__ wt) {
  int i = blockIdx.x * 256 + threadIdx.x;
  if (i >= COUT * KTOT) return;
  int co = i / KTOT, kp = i - co * KTOT;
  int kw = kp / 192, rem = kp - kw * 192;
  int ci = rem / 3, kh = rem - ci * 3;
  wt[i] = f2bf(w[co * 576 + ci * 9 + kh * 3 + kw]);
}

// One block per output row (n, oh). 128(co) x 128(pixel, 126 used) tile.
// 4 waves in 2x2: wave wc -> co half, wp -> pixel half; each wave 64x64 via
// 4x4 fragments of v_mfma_f32_16x16x32_bf16, K-loop of 18 steps.
template <bool USE_WT>
__global__ __launch_bounds__(256, 2)
void conv_min_kernel(const float* __restrict__ x,
                     const float* __restrict__ w,
                     const float* __restrict__ bias,
                     const unsigned short* __restrict__ wt,
                     float* __restrict__ out) {
  // row stride 40 ushorts = 80B = 5*16B: keeps b128 frag reads 16B-aligned,
  // breaks power-of-2 bank stride.
  __shared__ __align__(16) unsigned short sW[128][40];  // [co][kk]
  __shared__ __align__(16) unsigned short sX[128][40];  // [pixel][kk]
  __shared__ float sBias[COUT];
  __shared__ float sRed[2][128];

  const int t   = threadIdx.x;
  const int bid = blockIdx.x;
  const int n   = bid / OHh;
  const int oh  = bid - n * OHh;

  if (t < COUT) sBias[t] = bias[t];

  // staging roles
  const int hq = t & 7;        // kk-pair id (pairs 2h and 2h+16)
  const int q  = t >> 3;       // pixel quad 0..31
  const int c0 = q * 4;        // aligned source column
  const int wco   = t >> 1;    // W staging: output channel
  const int whalf = t & 1;     // W staging: k half (16 each)

  // mfma roles
  const int lane = t & 63, lg = lane >> 4, ln = lane & 15;
  const int wv = t >> 6, wc = wv & 1, wp = wv >> 1;

  f32x4 acc[4][4];
  #pragma unroll
  for (int i = 0; i < 4; ++i)
    #pragma unroll
    for (int j = 0; j < 4; ++j)
      acc[i][j] = (f32x4){0.f, 0.f, 0.f, 0.f};

  const float* xn = x + (size_t)n * CIN * CH * CW;

  for (int s = 0; s < NSTEPS; ++s) {
    const int k0 = s * KSTEP;
    const int kw_s = s / 6;               // kw constant within a K-step
    const int rembase = (s - kw_s * 6) * 32;

    // ---- global loads: x (aligned float4, column base c0; shift on write) ----
    float4 xa[2], xb[2];
    int kkp[2];
    #pragma unroll
    for (int pi = 0; pi < 2; ++pi) {
      const int kk = 2 * hq + 16 * pi;
      kkp[pi] = kk;
      int rem0 = rembase + kk;
      int ci0 = rem0 / 3, kh0 = rem0 - ci0 * 3;
      int rem1 = rem0 + 1;
      int ci1 = rem1 / 3, kh1 = rem1 - ci1 * 3;
      xa[pi] = *(const float4*)(xn + (ci0 * CH + (oh + kh0)) * CW + c0);
      xb[pi] = *(const float4*)(xn + (ci1 * CH + (oh + kh1)) * CW + c0);
    }

    // ---- global loads: W ----
    uint4 wv0, wv1;
    if constexpr (USE_WT) {
      const uint4* src = (const uint4*)(wt + wco * KTOT + k0 + whalf * 16);
      wv0 = src[0];
      wv1 = src[1];
    } else {
      unsigned tmp[8];
      #pragma unroll
      for (int e = 0; e < 8; ++e) {
        int kk = whalf * 16 + 2 * e;
        int rem0 = rembase + kk;
        int ci0 = rem0 / 3, kh0 = rem0 - ci0 * 3;
        int rem1 = rem0 + 1;
        int ci1 = rem1 / 3, kh1 = rem1 - ci1 * 3;
        float f0 = w[wco * 576 + ci0 * 9 + kh0 * 3 + kw_s];
        float f1 = w[wco * 576 + ci1 * 9 + kh1 * 3 + kw_s];
        tmp[e] = (unsigned)f2bf(f0) | ((unsigned)f2bf(f1) << 16);
      }
      wv0 = make_uint4(tmp[0], tmp[1], tmp[2], tmp[3]);
      wv1 = make_uint4(tmp[4], tmp[5], tmp[6], tmp[7]);
    }

    __syncthreads();  // previous step's fragment reads complete

    // ---- LDS writes: x, transposed to [pixel][kk], kw shift applied here ----
    #pragma unroll
    for (int pi = 0; pi < 2; ++pi) {
      #pragma unroll
      for (int j = 0; j < 4; ++j) {
        int p = c0 + j - kw_s;
        unsigned pk = (unsigned)f2bf(((const float*)&xa[pi])[j])
                    | ((unsigned)f2bf(((const float*)&xb[pi])[j]) << 16);
        if (p >= 0) *(unsigned*)&sX[p][kkp[pi]] = pk;
        // p in [0,125] always fully written; rows 126/127 are pad (never output)
      }
    }
    // ---- LDS writes: W ----
    *(uint4*)&sW[wco][whalf * 16]     = wv0;
    *(uint4*)&sW[wco][whalf * 16 + 8] = wv1;

    __syncthreads();

    // ---- fragments + MFMA ----
    bf16x8 af[4], bfr[4];
    #pragma unroll
    for (int mi = 0; mi < 4; ++mi)
      af[mi] = *(const bf16x8*)&sW[wc * 64 + mi * 16 + ln][lg * 8];
    #pragma unroll
    for (int ni = 0; ni < 4; ++ni)
      bfr[ni] = *(const bf16x8*)&sX[wp * 64 + ni * 16 + ln][lg * 8];
    #pragma unroll
    for (int mi = 0; mi < 4; ++mi)
      #pragma unroll
      for (int ni = 0; ni < 4; ++ni)
        acc[mi][ni] = __builtin_amdgcn_mfma_f32_16x16x32_bf16(
            af[mi], bfr[ni], acc[mi][ni], 0, 0, 0);
  }

  // ---- epilogue: (acc + bias) * 0.5, min over co ----
  // C/D layout (m89): col = lane&15 = pixel, row = (lane>>4)*4 + reg = co-in-frag
  float bv[4][4];
  #pragma unroll
  for (int mi = 0; mi < 4; ++mi)
    #pragma unroll
    for (int r = 0; r < 4; ++r)
      bv[mi][r] = sBias[wc * 64 + mi * 16 + lg * 4 + r];

  #pragma unroll
  for (int ni = 0; ni < 4; ++ni) {
    float m = 3.4e38f;
    #pragma unroll
    for (int mi = 0; mi < 4; ++mi)
      #pragma unroll
      for (int r = 0; r < 4; ++r) {
        float v = (acc[mi][ni][r] + bv[mi][r]) * 0.5f;
        m = fminf(m, v);
      }
    // min across the 4 lane-groups (co rows 4g..4g+3)
    m = fminf(m, __shfl_xor(m, 16));
    m = fminf(m, __shfl_xor(m, 32));
    if (lg == 0) sRed[wc][wp * 64 + ni * 16 + ln] = m;  // per-wave-half partial
  }
  __syncthreads();

  if (t < OWw) {
    out[(size_t)(n * OHh + oh) * OWw + t] = fminf(sRed[0][t], sRed[1][t]);
  }
}

extern "C" void kernel_launch(void* const* d_in, const int* in_sizes, int n_in,
                              void* d_out, int out_size, void* d_ws, size_t ws_size,
                              hipStream_t stream) {
  const float* x    = (const float*)d_in[0];
  const float* w    = (const float*)d_in[1];
  const float* bias = (const float*)d_in[2];
  float* out = (float*)d_out;

  const size_t WT_BYTES = (size_t)COUT * KTOT * sizeof(unsigned short);  // 147456

  if (d_ws && ws_size >= WT_BYTES) {
    unsigned short* wt = (unsigned short*)d_ws;
    prep_wt_kernel<<<(COUT * KTOT + 255) / 256, 256, 0, stream>>>(w, wt);
    conv_min_kernel<true><<<CN * OHh, 256, 0, stream>>>(x, w, bias, wt, out);
  } else {
    conv_min_kernel<false><<<CN * OHh, 256, 0, stream>>>(x, w, bias, nullptr, out);
  }
}

// Round 2
// 115.236 us; speedup vs baseline: 1.5777x; 1.5777x over previous
//
#include <hip/hip_runtime.h>

constexpr int CN   = 32;
constexpr int CIN  = 64;
constexpr int CH   = 128;
constexpr int CW   = 128;
constexpr int COUT = 128;
constexpr int OHh  = 126;
constexpr int OWw  = 126;
constexpr int KTOT = 576;

typedef __attribute__((ext_vector_type(8))) short bf16x8;
typedef __attribute__((ext_vector_type(4))) float f32x4;

__device__ __forceinline__ unsigned short f2bf(float f) {
  union { float f; unsigned u; } v; v.f = f;
  unsigned u = v.u;
  u += 0x7FFFu + ((u >> 16) & 1u);   // RNE
  return (unsigned short)(u >> 16);
}

__device__ __forceinline__ void gload_lds16(const unsigned short* g, unsigned short* l) {
  __builtin_amdgcn_global_load_lds(
      (const __attribute__((address_space(1))) unsigned int*)g,
      (__attribute__((address_space(3))) unsigned int*)l, 16, 0, 0);
}

// ---------------- prep: x (N,Ci,H,W) fp32 -> xt[n][h][c][ci] bf16, swizzle baked ----
// Within each 32-ci half, octet o is stored at slot o ^ ((c>>1)&3)  (T2 swizzle).
__global__ __launch_bounds__(256) void prep_xt_kernel(const float* __restrict__ x,
                                                      unsigned short* __restrict__ xt) {
  __shared__ __align__(16) unsigned short s[128][72];  // row 144B, 16B-aligned
  const int b = blockIdx.x;            // n*128 + h
  const int n = b >> 7, h = b & 127;
  const float* src = x + (size_t)n * CIN * CH * CW + (size_t)h * CW;
  const int t = threadIdx.x;
  #pragma unroll
  for (int r = 0; r < 8; ++r) {
    int idx = r * 256 + t;             // 0..2047 float4s
    int ci = idx >> 5, c0 = (idx & 31) << 2;
    float4 v = *(const float4*)(src + (size_t)ci * (CH * CW) + c0);
    s[c0 + 0][ci] = f2bf(v.x);
    s[c0 + 1][ci] = f2bf(v.y);
    s[c0 + 2][ci] = f2bf(v.z);
    s[c0 + 3][ci] = f2bf(v.w);
  }
  __syncthreads();
  unsigned short* dst = xt + (size_t)b * 8192;   // 128 c * 64 ci
  #pragma unroll
  for (int r = 0; r < 4; ++r) {
    int idx = r * 256 + t;             // 0..1023 16B-octets
    int c = idx >> 3, sl = idx & 7;
    int half = sl >> 2, q = sl & 3;
    int lo = q ^ ((c >> 1) & 3);       // logical octet stored at slot q
    uint4 v = *(const uint4*)&s[c][half * 32 + lo * 8];
    *(uint4*)(dst + (size_t)c * 64 + sl * 8) = v;
  }
}

// ---------------- prep: W (Co,Ci,3,3) fp32 -> wt[co][kw*192+kh*64+half*32+slot*8+j] ----
__global__ void prep_wt2_kernel(const float* __restrict__ w,
                                unsigned short* __restrict__ wt) {
  int i = blockIdx.x * 256 + threadIdx.x;
  if (i >= COUT * KTOT) return;
  int co = i / KTOT, k = i - co * KTOT;
  int kw = k / 192, r = k - kw * 192;
  int kh = r >> 6, q = r & 63;
  int half = q >> 5, qq = q & 31;
  int sl = qq >> 3, j = qq & 7;
  int o = sl ^ ((co >> 1) & 3);        // slot sl holds logical octet o
  int ci = half * 32 + o * 8 + j;
  wt[i] = f2bf(w[co * 576 + ci * 9 + kh * 3 + kw]);
}

// ---------------- main: implicit GEMM, kw-reused X tile, counted-vmcnt pipeline ------
__global__ __launch_bounds__(256, 2)
void conv_min_mfma(const unsigned short* __restrict__ xt,
                   const unsigned short* __restrict__ wt,
                   const float* __restrict__ bias,
                   float* __restrict__ out) {
  __shared__ __align__(16) unsigned short sX[2][132][32];      // rows 128..131 = pad
  __shared__ __align__(16) unsigned short sW[2][3][128][32];
  __shared__ float sBias[COUT];
  __shared__ float sRed[2][128];

  const int t = threadIdx.x;
  const int bid = blockIdx.x;
  const int swz = (bid & 7) * 504 + (bid >> 3);   // XCD-contiguous, 4032 = 8*504
  const int n = swz / OHh;
  const int oh = swz - n * OHh;

  if (t < COUT) sBias[t] = bias[t];

  const int lane = t & 63;
  const int w = t >> 6;
  const int wc = w & 1, wp = w >> 1;
  const int lg = lane >> 4, ln = lane & 15;

  // staging lane-invariant offsets (slot-preserving linear copy; swizzle is baked)
  int xoff[2], xslotb[2];
  #pragma unroll
  for (int r = 0; r < 2; ++r) {
    int slotb = (r * 4 + w) * 64;
    int slot = slotb + lane;
    xslotb[r] = slotb;
    xoff[r] = (slot >> 2) * 64 + (slot & 3) * 8;
  }
  int woff[6], wslotb[6];
  #pragma unroll
  for (int r = 0; r < 6; ++r) {
    int slotb = (r * 4 + w) * 64;
    int slot = slotb + lane;
    wslotb[r] = slotb;
    int kw = slot >> 9, co = (slot >> 2) & 127, q4 = slot & 3;
    woff[r] = co * 576 + kw * 192 + q4 * 8;
  }

  // fragment read bases (swizzled chunk per row)
  const unsigned short* Abase[4];
  #pragma unroll
  for (int mi = 0; mi < 4; ++mi) {
    int co = wc * 64 + mi * 16 + ln;
    int ch = lg ^ ((co >> 1) & 3);
    Abase[mi] = &sW[0][0][co][ch * 8];
  }
  const unsigned short* Bbase[3][4];
  #pragma unroll
  for (int kw = 0; kw < 3; ++kw)
    #pragma unroll
    for (int ni = 0; ni < 4; ++ni) {
      int row = wp * 64 + ni * 16 + ln + kw;   // <=129, pad rows finite-garbage only
      int ch = lg ^ ((row >> 1) & 3);
      Bbase[kw][ni] = &sX[0][row][ch * 8];
    }

  f32x4 acc[4][4];
  #pragma unroll
  for (int i = 0; i < 4; ++i)
    #pragma unroll
    for (int j = 0; j < 4; ++j)
      acc[i][j] = (f32x4){0.f, 0.f, 0.f, 0.f};

  auto stage = [&](int g, int bf) {
    const int h = oh + (g >> 1);
    const int half = g & 1;
    const size_t xb = ((size_t)(n * 128 + h)) * 8192 + half * 32;
    const int wb = (g >> 1) * 64 + half * 32;
    unsigned short* ldsX = &sX[bf][0][0];
    unsigned short* ldsW = &sW[bf][0][0][0];
    #pragma unroll
    for (int r = 0; r < 2; ++r)
      gload_lds16(xt + xb + xoff[r], ldsX + xslotb[r] * 8);
    #pragma unroll
    for (int r = 0; r < 6; ++r)
      gload_lds16(wt + wb + woff[r], ldsW + wslotb[r] * 8);
  };

  stage(0, 0);
  #pragma unroll
  for (int g = 0; g < 6; ++g) {
    const int bf = g & 1;
    if (g < 5) {
      stage(g + 1, bf ^ 1);
      __builtin_amdgcn_sched_barrier(0);
      asm volatile("s_waitcnt vmcnt(8)" ::: "memory");  // my stage(g) landed
    } else {
      asm volatile("s_waitcnt vmcnt(0)" ::: "memory");
    }
    __builtin_amdgcn_s_barrier();                        // everyone's stage(g) landed
    __builtin_amdgcn_sched_barrier(0);
    #pragma unroll
    for (int kw = 0; kw < 3; ++kw) {
      bf16x8 af[4], bfr[4];
      #pragma unroll
      for (int mi = 0; mi < 4; ++mi)
        af[mi] = *(const bf16x8*)(Abase[mi] + bf * 12288 + kw * 4096);
      #pragma unroll
      for (int ni = 0; ni < 4; ++ni)
        bfr[ni] = *(const bf16x8*)(Bbase[kw][ni] + bf * 4224);
      #pragma unroll
      for (int mi = 0; mi < 4; ++mi)
        #pragma unroll
        for (int ni = 0; ni < 4; ++ni)
          acc[mi][ni] = __builtin_amdgcn_mfma_f32_16x16x32_bf16(
              af[mi], bfr[ni], acc[mi][ni], 0, 0, 0);
    }
    __builtin_amdgcn_s_barrier();                        // buffer reusable
  }

  // epilogue: (acc + bias)*0.5, min over co. C/D: col=lane&15=pixel, row=lg*4+r=co
  #pragma unroll
  for (int ni = 0; ni < 4; ++ni) {
    float m = 3.4e38f;
    #pragma unroll
    for (int mi = 0; mi < 4; ++mi)
      #pragma unroll
      for (int r = 0; r < 4; ++r) {
        float v = (acc[mi][ni][r] + sBias[wc * 64 + mi * 16 + lg * 4 + r]) * 0.5f;
        m = fminf(m, v);
      }
    m = fminf(m, __shfl_xor(m, 16));
    m = fminf(m, __shfl_xor(m, 32));
    if (lg == 0) sRed[wc][wp * 64 + ni * 16 + ln] = m;
  }
  __syncthreads();
  if (t < OWw)
    out[(size_t)(n * OHh + oh) * OWw + t] = fminf(sRed[0][t], sRed[1][t]);
}

// ================= fallback (round-1 kernel, used only if ws too small) =============
__global__ void prep_wt_kernel(const float* __restrict__ w,
                               unsigned short* __restrict__ wt) {
  int i = blockIdx.x * 256 + threadIdx.x;
  if (i >= COUT * KTOT) return;
  int co = i / KTOT, kp = i - co * KTOT;
  int kw = kp / 192, rem = kp - kw * 192;
  int ci = rem / 3, kh = rem - ci * 3;
  wt[i] = f2bf(w[co * 576 + ci * 9 + kh * 3 + kw]);
}

template <bool USE_WT>
__global__ __launch_bounds__(256, 2)
void conv_min_fb(const float* __restrict__ x, const float* __restrict__ w,
                 const float* __restrict__ bias, const unsigned short* __restrict__ wt,
                 float* __restrict__ out) {
  __shared__ __align__(16) unsigned short sW[128][40];
  __shared__ __align__(16) unsigned short sX[128][40];
  __shared__ float sBias[COUT];
  __shared__ float sRed[2][128];
  const int t = threadIdx.x, bid = blockIdx.x;
  const int n = bid / OHh, oh = bid - n * OHh;
  if (t < COUT) sBias[t] = bias[t];
  const int hq = t & 7, q = t >> 3, c0 = q * 4;
  const int wco = t >> 1, whalf = t & 1;
  const int lane = t & 63, lg = lane >> 4, ln = lane & 15;
  const int wv = t >> 6, wc = wv & 1, wp = wv >> 1;
  f32x4 acc[4][4];
  #pragma unroll
  for (int i = 0; i < 4; ++i)
    #pragma unroll
    for (int j = 0; j < 4; ++j) acc[i][j] = (f32x4){0.f, 0.f, 0.f, 0.f};
  const float* xn = x + (size_t)n * CIN * CH * CW;
  for (int s = 0; s < 18; ++s) {
    const int k0 = s * 32;
    const int kw_s = s / 6;
    const int rembase = (s - kw_s * 6) * 32;
    float4 xa[2], xb[2]; int kkp[2];
    #pragma unroll
    for (int pi = 0; pi < 2; ++pi) {
      const int kk = 2 * hq + 16 * pi; kkp[pi] = kk;
      int rem0 = rembase + kk, ci0 = rem0 / 3, kh0 = rem0 - ci0 * 3;
      int rem1 = rem0 + 1, ci1 = rem1 / 3, kh1 = rem1 - ci1 * 3;
      xa[pi] = *(const float4*)(xn + (ci0 * CH + (oh + kh0)) * CW + c0);
      xb[pi] = *(const float4*)(xn + (ci1 * CH + (oh + kh1)) * CW + c0);
    }
    uint4 wv0, wv1;
    if constexpr (USE_WT) {
      const uint4* src = (const uint4*)(wt + wco * KTOT + k0 + whalf * 16);
      wv0 = src[0]; wv1 = src[1];
    } else {
      unsigned tmp[8];
      #pragma unroll
      for (int e = 0; e < 8; ++e) {
        int kk = whalf * 16 + 2 * e;
        int rem0 = rembase + kk, ci0 = rem0 / 3, kh0 = rem0 - ci0 * 3;
        int rem1 = rem0 + 1, ci1 = rem1 / 3, kh1 = rem1 - ci1 * 3;
        tmp[e] = (unsigned)f2bf(w[wco * 576 + ci0 * 9 + kh0 * 3 + kw_s]) |
                 ((unsigned)f2bf(w[wco * 576 + ci1 * 9 + kh1 * 3 + kw_s]) << 16);
      }
      wv0 = make_uint4(tmp[0], tmp[1], tmp[2], tmp[3]);
      wv1 = make_uint4(tmp[4], tmp[5], tmp[6], tmp[7]);
    }
    __syncthreads();
    #pragma unroll
    for (int pi = 0; pi < 2; ++pi)
      #pragma unroll
      for (int j = 0; j < 4; ++j) {
        int p = c0 + j - kw_s;
        unsigned pk = (unsigned)f2bf(((const float*)&xa[pi])[j]) |
                      ((unsigned)f2bf(((const float*)&xb[pi])[j]) << 16);
        if (p >= 0) *(unsigned*)&sX[p][kkp[pi]] = pk;
      }
    *(uint4*)&sW[wco][whalf * 16] = wv0;
    *(uint4*)&sW[wco][whalf * 16 + 8] = wv1;
    __syncthreads();
    bf16x8 af[4], bfr[4];
    #pragma unroll
    for (int mi = 0; mi < 4; ++mi) af[mi] = *(const bf16x8*)&sW[wc * 64 + mi * 16 + ln][lg * 8];
    #pragma unroll
    for (int ni = 0; ni < 4; ++ni) bfr[ni] = *(const bf16x8*)&sX[wp * 64 + ni * 16 + ln][lg * 8];
    #pragma unroll
    for (int mi = 0; mi < 4; ++mi)
      #pragma unroll
      for (int ni = 0; ni < 4; ++ni)
        acc[mi][ni] = __builtin_amdgcn_mfma_f32_16x16x32_bf16(af[mi], bfr[ni], acc[mi][ni], 0, 0, 0);
  }
  #pragma unroll
  for (int ni = 0; ni < 4; ++ni) {
    float m = 3.4e38f;
    #pragma unroll
    for (int mi = 0; mi < 4; ++mi)
      #pragma unroll
      for (int r = 0; r < 4; ++r)
        m = fminf(m, (acc[mi][ni][r] + sBias[wc * 64 + mi * 16 + lg * 4 + r]) * 0.5f);
    m = fminf(m, __shfl_xor(m, 16));
    m = fminf(m, __shfl_xor(m, 32));
    if (lg == 0) sRed[wc][wp * 64 + ni * 16 + ln] = m;
  }
  __syncthreads();
  if (t < OWw) out[(size_t)(n * OHh + oh) * OWw + t] = fminf(sRed[0][t], sRed[1][t]);
}

extern "C" void kernel_launch(void* const* d_in, const int* in_sizes, int n_in,
                              void* d_out, int out_size, void* d_ws, size_t ws_size,
                              hipStream_t stream) {
  const float* x    = (const float*)d_in[0];
  const float* w    = (const float*)d_in[1];
  const float* bias = (const float*)d_in[2];
  float* out = (float*)d_out;

  const size_t XT_BYTES = (size_t)CN * CH * CW * CIN * 2;  // 67,108,864
  const size_t WT_BYTES = (size_t)COUT * KTOT * 2;         // 147,456

  if (d_ws && ws_size >= XT_BYTES + WT_BYTES) {
    unsigned short* xt = (unsigned short*)d_ws;
    unsigned short* wt = (unsigned short*)((char*)d_ws + XT_BYTES);
    prep_xt_kernel<<<CN * CH, 256, 0, stream>>>(x, xt);
    prep_wt2_kernel<<<(COUT * KTOT + 255) / 256, 256, 0, stream>>>(w, wt);
    conv_min_mfma<<<CN * OHh, 256, 0, stream>>>(xt, wt, bias, out);
  } else if (d_ws && ws_size >= WT_BYTES) {
    unsigned short* wt = (unsigned short*)d_ws;
    prep_wt_kernel<<<(COUT * KTOT + 255) / 256, 256, 0, stream>>>(w, wt);
    conv_min_fb<true><<<CN * OHh, 256, 0, stream>>>(x, w, bias, wt, out);
  } else {
    conv_min_fb<false><<<CN * OHh, 256, 0, stream>>>(x, w, bias, nullptr, out);
  }
}

// Round 3
// 104.524 us; speedup vs baseline: 1.7394x; 1.1025x over previous
//
#include <hip/hip_runtime.h>

constexpr int CN   = 32;
constexpr int CIN  = 64;
constexpr int CH   = 128;
constexpr int CW   = 128;
constexpr int COUT = 128;
constexpr int OHh  = 126;
constexpr int OWw  = 126;
constexpr int KTOT = 576;

typedef __attribute__((ext_vector_type(8))) short bf16x8;
typedef __attribute__((ext_vector_type(4))) float f32x4;

__device__ __forceinline__ unsigned short f2bf(float f) {
  union { float f; unsigned u; } v; v.f = f;
  unsigned u = v.u;
  u += 0x7FFFu + ((u >> 16) & 1u);   // RNE
  return (unsigned short)(u >> 16);
}

__device__ __forceinline__ void gload_lds16(const unsigned short* g, unsigned short* l) {
  __builtin_amdgcn_global_load_lds(
      (const __attribute__((address_space(1))) unsigned int*)g,
      (__attribute__((address_space(3))) unsigned int*)l, 16, 0, 0);
}

// ---- prep: x (N,Ci,H,W) fp32 -> xt[n][h][c][ci] bf16, T2 swizzle baked --------------
// Within each 32-ci half, logical octet o stored at slot o ^ ((c>>1)&3).
__global__ __launch_bounds__(256) void prep_xt_kernel(const float* __restrict__ x,
                                                      unsigned short* __restrict__ xt) {
  __shared__ __align__(16) unsigned short s[128][72];
  const int b = blockIdx.x;            // n*128 + h
  const int n = b >> 7, h = b & 127;
  const float* src = x + (size_t)n * CIN * CH * CW + (size_t)h * CW;
  const int t = threadIdx.x;
  #pragma unroll
  for (int r = 0; r < 8; ++r) {
    int idx = r * 256 + t;
    int ci = idx >> 5, c0 = (idx & 31) << 2;
    float4 v = *(const float4*)(src + (size_t)ci * (CH * CW) + c0);
    s[c0 + 0][ci] = f2bf(v.x);
    s[c0 + 1][ci] = f2bf(v.y);
    s[c0 + 2][ci] = f2bf(v.z);
    s[c0 + 3][ci] = f2bf(v.w);
  }
  __syncthreads();
  unsigned short* dst = xt + (size_t)b * 8192;
  #pragma unroll
  for (int r = 0; r < 4; ++r) {
    int idx = r * 256 + t;
    int c = idx >> 3, sl = idx & 7;
    int half = sl >> 2, q = sl & 3;
    int lo = q ^ ((c >> 1) & 3);
    uint4 v = *(const uint4*)&s[c][half * 32 + lo * 8];
    *(uint4*)(dst + (size_t)c * 64 + sl * 8) = v;
  }
}

// ---- prep: W -> wt[co][kw*192 + kh*64 + half*32 + slot*8 + j], swizzle baked --------
__global__ void prep_wt2_kernel(const float* __restrict__ w,
                                unsigned short* __restrict__ wt) {
  int i = blockIdx.x * 256 + threadIdx.x;
  if (i >= COUT * KTOT) return;
  int co = i / KTOT, k = i - co * KTOT;
  int kw = k / 192, r = k - kw * 192;
  int kh = r >> 6, q = r & 63;
  int half = q >> 5, qq = q & 31;
  int sl = qq >> 3, j = qq & 7;
  int o = sl ^ ((co >> 1) & 3);
  int ci = half * 32 + o * 8 + j;
  wt[i] = f2bf(w[co * 576 + ci * 9 + kh * 3 + kw]);
}

// ---- main: 512 thr, 8 waves (2co x 4px-rows), M=128 x N=512 (4 output rows) ---------
__global__ __launch_bounds__(512, 2)
void conv_min_mfma4(const unsigned short* __restrict__ xt,
                    const unsigned short* __restrict__ wt,
                    const float* __restrict__ bias,
                    float* __restrict__ out) {
  __shared__ __align__(16) unsigned short sX[2][4][132][32];   // [bf][row][c(pad)][ci-half]
  __shared__ __align__(16) unsigned short sW[2][3][128][32];   // [bf][kw][co][ci-half]
  __shared__ float sRed[2][512];

  const int t   = threadIdx.x;
  const int bid = blockIdx.x;
  const int swz = (bid & 7) * 128 + (bid >> 3);   // 1024 = 8*128, bijective
  const int n   = swz >> 5;
  const int oh0 = (swz & 31) * 4;

  const int lane = t & 63, w = t >> 6;
  const int wc = w & 1, wp = w >> 1;              // co-half, px-row
  const int lg = lane >> 4, ln = lane & 15;

  // staging: lane-dependent global offsets (r-invariant)
  const int xcq   = (t >> 2) * 64 + (t & 3) * 8;          // c = t>>2, q4 = t&3
  const int wco_o = (t >> 2) * 576 + (t & 3) * 8;         // co = t>>2

  // fragment read base byte-offsets (swizzle chunks are mi-/ni-invariant)
  const int chA = lg ^ ((ln >> 1) & 3);
  const char* Abase = (const char*)&sW[0][0][0][0] +
                      ((wc * 64 + ln) * 64 + chA * 16);   // + bf*24576 + kw*8192 + mi*1024
  const char* Bbase[3];
  #pragma unroll
  for (int kw = 0; kw < 3; ++kw) {
    int chB = lg ^ (((ln + kw) >> 1) & 3);
    Bbase[kw] = (const char*)&sX[0][0][0][0] +
                (wp * 8448 + (ln + kw) * 64 + chB * 16);  // + bf*33792 + ni*1024
  }

  f32x4 acc[4][8];
  #pragma unroll
  for (int i = 0; i < 4; ++i)
    #pragma unroll
    for (int j = 0; j < 8; ++j)
      acc[i][j] = (f32x4){0.f, 0.f, 0.f, 0.f};

  auto stage = [&](int g, int bf) {
    const int kh = g >> 1, half = g & 1;
    unsigned short* ldsX = &sX[bf][0][0][0];
    unsigned short* ldsW = &sW[bf][0][0][0];
    #pragma unroll
    for (int r = 0; r < 4; ++r) {
      int h = oh0 + kh + r;
      h = h > 127 ? 127 : h;                       // tail clamp (masked at store)
      gload_lds16(xt + ((size_t)(n * 128 + h) << 13) + half * 32 + xcq,
                  ldsX + r * 4224 + w * 512);
    }
    const int wb = kh * 64 + half * 32;
    #pragma unroll
    for (int r = 0; r < 3; ++r)
      gload_lds16(wt + wb + wco_o + r * 192,
                  ldsW + r * 4096 + w * 512);
  };

  stage(0, 0);
  #pragma unroll
  for (int g = 0; g < 6; ++g) {
    const int bf = g & 1;
    if (g < 5) {
      stage(g + 1, bf ^ 1);
      __builtin_amdgcn_sched_barrier(0);
      asm volatile("s_waitcnt vmcnt(7)" ::: "memory");   // my stage(g) landed
    } else {
      asm volatile("s_waitcnt vmcnt(0)" ::: "memory");
    }
    __builtin_amdgcn_s_barrier();                        // everyone's stage(g) landed
    __builtin_amdgcn_sched_barrier(0);
    #pragma unroll
    for (int kw = 0; kw < 3; ++kw) {
      bf16x8 af[4], bfr[8];
      #pragma unroll
      for (int mi = 0; mi < 4; ++mi)
        af[mi] = *(const bf16x8*)(Abase + bf * 24576 + kw * 8192 + mi * 1024);
      #pragma unroll
      for (int ni = 0; ni < 8; ++ni)
        bfr[ni] = *(const bf16x8*)(Bbase[kw] + bf * 33792 + ni * 1024);
      #pragma unroll
      for (int mi = 0; mi < 4; ++mi)
        #pragma unroll
        for (int ni = 0; ni < 8; ++ni)
          acc[mi][ni] = __builtin_amdgcn_mfma_f32_16x16x32_bf16(
              af[mi], bfr[ni], acc[mi][ni], 0, 0, 0);
    }
    __builtin_amdgcn_s_barrier();                        // buffer bf reusable
  }

  // epilogue: (acc + bias)*0.5, min over co
  // C/D: col = ln = px within ni-frag, row = lg*4 + r = co within mi-frag
  float bv[4][4];
  #pragma unroll
  for (int mi = 0; mi < 4; ++mi)
    #pragma unroll
    for (int r = 0; r < 4; ++r)
      bv[mi][r] = bias[wc * 64 + mi * 16 + lg * 4 + r];

  #pragma unroll
  for (int ni = 0; ni < 8; ++ni) {
    float m = 3.4e38f;
    #pragma unroll
    for (int mi = 0; mi < 4; ++mi)
      #pragma unroll
      for (int r = 0; r < 4; ++r)
        m = fminf(m, (acc[mi][ni][r] + bv[mi][r]) * 0.5f);
    m = fminf(m, __shfl_xor(m, 16));
    m = fminf(m, __shfl_xor(m, 32));
    if (lg == 0) sRed[wc][wp * 128 + ni * 16 + ln] = m;
  }
  __syncthreads();
  {
    int row = t >> 7, c = t & 127;
    if (c < OWw && oh0 + row < OHh)
      out[((size_t)n * OHh + oh0 + row) * OWw + c] = fminf(sRed[0][t], sRed[1][t]);
  }
}

// ================= fallbacks (round-1 path, used only if ws too small) ==============
__global__ void prep_wt_kernel(const float* __restrict__ w,
                               unsigned short* __restrict__ wt) {
  int i = blockIdx.x * 256 + threadIdx.x;
  if (i >= COUT * KTOT) return;
  int co = i / KTOT, kp = i - co * KTOT;
  int kw = kp / 192, rem = kp - kw * 192;
  int ci = rem / 3, kh = rem - ci * 3;
  wt[i] = f2bf(w[co * 576 + ci * 9 + kh * 3 + kw]);
}

template <bool USE_WT>
__global__ __launch_bounds__(256, 2)
void conv_min_fb(const float* __restrict__ x, const float* __restrict__ w,
                 const float* __restrict__ bias, const unsigned short* __restrict__ wt,
                 float* __restrict__ out) {
  __shared__ __align__(16) unsigned short sW[128][40];
  __shared__ __align__(16) unsigned short sX[128][40];
  __shared__ float sBias[COUT];
  __shared__ float sRed[2][128];
  const int t = threadIdx.x, bid = blockIdx.x;
  const int n = bid / OHh, oh = bid - n * OHh;
  if (t < COUT) sBias[t] = bias[t];
  const int hq = t & 7, q = t >> 3, c0 = q * 4;
  const int wco = t >> 1, whalf = t & 1;
  const int lane = t & 63, lg = lane >> 4, ln = lane & 15;
  const int wv = t >> 6, wc = wv & 1, wp = wv >> 1;
  f32x4 acc[4][4];
  #pragma unroll
  for (int i = 0; i < 4; ++i)
    #pragma unroll
    for (int j = 0; j < 4; ++j) acc[i][j] = (f32x4){0.f, 0.f, 0.f, 0.f};
  const float* xn = x + (size_t)n * CIN * CH * CW;
  for (int s = 0; s < 18; ++s) {
    const int k0 = s * 32;
    const int kw_s = s / 6;
    const int rembase = (s - kw_s * 6) * 32;
    float4 xa[2], xb[2]; int kkp[2];
    #pragma unroll
    for (int pi = 0; pi < 2; ++pi) {
      const int kk = 2 * hq + 16 * pi; kkp[pi] = kk;
      int rem0 = rembase + kk, ci0 = rem0 / 3, kh0 = rem0 - ci0 * 3;
      int rem1 = rem0 + 1, ci1 = rem1 / 3, kh1 = rem1 - ci1 * 3;
      xa[pi] = *(const float4*)(xn + (ci0 * CH + (oh + kh0)) * CW + c0);
      xb[pi] = *(const float4*)(xn + (ci1 * CH + (oh + kh1)) * CW + c0);
    }
    uint4 wv0, wv1;
    if constexpr (USE_WT) {
      const uint4* src = (const uint4*)(wt + wco * KTOT + k0 + whalf * 16);
      wv0 = src[0]; wv1 = src[1];
    } else {
      unsigned tmp[8];
      #pragma unroll
      for (int e = 0; e < 8; ++e) {
        int kk = whalf * 16 + 2 * e;
        int rem0 = rembase + kk, ci0 = rem0 / 3, kh0 = rem0 - ci0 * 3;
        int rem1 = rem0 + 1, ci1 = rem1 / 3, kh1 = rem1 - ci1 * 3;
        tmp[e] = (unsigned)f2bf(w[wco * 576 + ci0 * 9 + kh0 * 3 + kw_s]) |
                 ((unsigned)f2bf(w[wco * 576 + ci1 * 9 + kh1 * 3 + kw_s]) << 16);
      }
      wv0 = make_uint4(tmp[0], tmp[1], tmp[2], tmp[3]);
      wv1 = make_uint4(tmp[4], tmp[5], tmp[6], tmp[7]);
    }
    __syncthreads();
    #pragma unroll
    for (int pi = 0; pi < 2; ++pi)
      #pragma unroll
      for (int j = 0; j < 4; ++j) {
        int p = c0 + j - kw_s;
        unsigned pk = (unsigned)f2bf(((const float*)&xa[pi])[j]) |
                      ((unsigned)f2bf(((const float*)&xb[pi])[j]) << 16);
        if (p >= 0) *(unsigned*)&sX[p][kkp[pi]] = pk;
      }
    *(uint4*)&sW[wco][whalf * 16] = wv0;
    *(uint4*)&sW[wco][whalf * 16 + 8] = wv1;
    __syncthreads();
    bf16x8 af[4], bfr[4];
    #pragma unroll
    for (int mi = 0; mi < 4; ++mi) af[mi] = *(const bf16x8*)&sW[wc * 64 + mi * 16 + ln][lg * 8];
    #pragma unroll
    for (int ni = 0; ni < 4; ++ni) bfr[ni] = *(const bf16x8*)&sX[wp * 64 + ni * 16 + ln][lg * 8];
    #pragma unroll
    for (int mi = 0; mi < 4; ++mi)
      #pragma unroll
      for (int ni = 0; ni < 4; ++ni)
        acc[mi][ni] = __builtin_amdgcn_mfma_f32_16x16x32_bf16(af[mi], bfr[ni], acc[mi][ni], 0, 0, 0);
  }
  #pragma unroll
  for (int ni = 0; ni < 4; ++ni) {
    float m = 3.4e38f;
    #pragma unroll
    for (int mi = 0; mi < 4; ++mi)
      #pragma unroll
      for (int r = 0; r < 4; ++r)
        m = fminf(m, (acc[mi][ni][r] + sBias[wc * 64 + mi * 16 + lg * 4 + r]) * 0.5f);
    m = fminf(m, __shfl_xor(m, 16));
    m = fminf(m, __shfl_xor(m, 32));
    if (lg == 0) sRed[wc][wp * 64 + ni * 16 + ln] = m;
  }
  __syncthreads();
  if (t < OWw) out[(size_t)(n * OHh + oh) * OWw + t] = fminf(sRed[0][t], sRed[1][t]);
}

extern "C" void kernel_launch(void* const* d_in, const int* in_sizes, int n_in,
                              void* d_out, int out_size, void* d_ws, size_t ws_size,
                              hipStream_t stream) {
  const float* x    = (const float*)d_in[0];
  const float* w    = (const float*)d_in[1];
  const float* bias = (const float*)d_in[2];
  float* out = (float*)d_out;

  const size_t XT_BYTES = (size_t)CN * CH * CW * CIN * 2;  // 67,108,864
  const size_t WT_BYTES = (size_t)COUT * KTOT * 2;         // 147,456

  if (d_ws && ws_size >= XT_BYTES + WT_BYTES) {
    unsigned short* xt = (unsigned short*)d_ws;
    unsigned short* wt = (unsigned short*)((char*)d_ws + XT_BYTES);
    prep_xt_kernel<<<CN * CH, 256, 0, stream>>>(x, xt);
    prep_wt2_kernel<<<(COUT * KTOT + 255) / 256, 256, 0, stream>>>(w, wt);
    conv_min_mfma4<<<1024, 512, 0, stream>>>(xt, wt, bias, out);
  } else if (d_ws && ws_size >= WT_BYTES) {
    unsigned short* wt = (unsigned short*)d_ws;
    prep_wt_kernel<<<(COUT * KTOT + 255) / 256, 256, 0, stream>>>(w, wt);
    conv_min_fb<true><<<CN * OHh, 256, 0, stream>>>(x, w, bias, wt, out);
  } else {
    conv_min_fb<false><<<CN * OHh, 256, 0, stream>>>(x, w, bias, nullptr, out);
  }
}